// Round 7
// baseline (386.733 us; speedup 1.0000x reference)
//
#include <hip/hip_runtime.h>

typedef __attribute__((ext_vector_type(8))) _Float16 half8;
typedef __attribute__((ext_vector_type(4))) _Float16 half4;
typedef __attribute__((ext_vector_type(4))) float f32x4;

#define CDIM 256
#define NDIM 4096
#define MFMAH(a, b, c) __builtin_amdgcn_mfma_f32_16x16x32_f16((a), (b), (c), 0, 0, 0)

// async global->LDS DMA, 16B per lane (spill-proof staging path)
#define GLOAD_LDS16(gp, lp)                                              \
  __builtin_amdgcn_global_load_lds(                                      \
      (const __attribute__((address_space(1))) void*)(gp),               \
      (__attribute__((address_space(3))) void*)(lp), 16, 0, 0)

// ---------------------------------------------------------------------------
// Cast W matrices to fp16 once per launch (L2-resident afterwards).
// ---------------------------------------------------------------------------
__global__ void cast_w_kernel(const float* __restrict__ Wq,
                              const float* __restrict__ Wk,
                              const float* __restrict__ Wv,
                              _Float16* __restrict__ Wc) {
  int t = blockIdx.x * 256 + threadIdx.x;      // 49152 float4 groups total
  int mat = t >> 14;                            // /16384
  int idx = (t & 16383) * 4;
  const float* W = (mat == 0) ? Wq : (mat == 1 ? Wk : Wv);
  float4 w = *(const float4*)(W + idx);
  half4 h = {(_Float16)w.x, (_Float16)w.y, (_Float16)w.z, (_Float16)w.w};
  *(half4*)(Wc + mat * 65536 + idx) = h;
}

// ---------------------------------------------------------------------------
// Projection (round-6 version, perf-neutral vs round-0): Y = W X + b
// Q,K -> [b][n][c]; V -> [b][c][n].
// ---------------------------------------------------------------------------
__global__ __launch_bounds__(256, 2) void proj_kernel(
    const float* __restrict__ queries, const float* __restrict__ keys,
    const _Float16* __restrict__ Wc,
    const float* __restrict__ bq, const float* __restrict__ bk,
    const float* __restrict__ bv,
    _Float16* __restrict__ Qh, _Float16* __restrict__ Kh,
    _Float16* __restrict__ Vh)
{
  const int z = blockIdx.z, p = z >> 3, b = z & 7;
  const float* __restrict__ X = (p == 0) ? queries : keys;
  const _Float16* __restrict__ W = Wc + p * 65536;
  const float* __restrict__ bias = (p == 0) ? bq : (p == 1 ? bk : bv);
  const int n0 = blockIdx.x * 128;

  __shared__ __align__(16) _Float16 Xs[128][264];  // [n][c^swz], 528 B rows

  const int tid = threadIdx.x;
  const int wv = tid >> 6, lane = tid & 63, l16 = lane & 15, quad = lane >> 4;

#pragma unroll
  for (int it = 0; it < 8; ++it) {
    int id = tid + it * 256;
    int n4 = id & 31, c0 = (id >> 5) * 4;
    const float* Xp = &X[((size_t)(b * CDIM + c0)) * NDIM + n0 + n4 * 4];
    float4 x0 = *(const float4*)(Xp);
    float4 x1 = *(const float4*)(Xp + NDIM);
    float4 x2 = *(const float4*)(Xp + 2 * NDIM);
    float4 x3 = *(const float4*)(Xp + 3 * NDIM);
    const int cs = c0 ^ ((n4 & 7) << 3);
    half4 h;
    h = (half4){(_Float16)x0.x, (_Float16)x1.x, (_Float16)x2.x, (_Float16)x3.x};
    *(half4*)&Xs[n4 * 4 + 0][cs] = h;
    h = (half4){(_Float16)x0.y, (_Float16)x1.y, (_Float16)x2.y, (_Float16)x3.y};
    *(half4*)&Xs[n4 * 4 + 1][cs] = h;
    h = (half4){(_Float16)x0.z, (_Float16)x1.z, (_Float16)x2.z, (_Float16)x3.z};
    *(half4*)&Xs[n4 * 4 + 2][cs] = h;
    h = (half4){(_Float16)x0.w, (_Float16)x1.w, (_Float16)x2.w, (_Float16)x3.w};
    *(half4*)&Xs[n4 * 4 + 3][cs] = h;
  }
  __syncthreads();

  f32x4 acc[4][8];
#pragma unroll
  for (int og = 0; og < 4; ++og)
#pragma unroll
    for (int ng = 0; ng < 8; ++ng) acc[og][ng] = (f32x4){0.f, 0.f, 0.f, 0.f};

#pragma unroll
  for (int kc = 0; kc < 8; ++kc) {
    half8 wf[4], xf[8];
#pragma unroll
    for (int og = 0; og < 4; ++og)
      wf[og] = *(const half8*)(W + (wv * 64 + og * 16 + l16) * CDIM + kc * 32 + quad * 8);
#pragma unroll
    for (int ng = 0; ng < 8; ++ng) {
      const int row = ng * 16 + l16;
      xf[ng] = *(const half8*)&Xs[row][(kc * 32 + quad * 8) ^ (((row >> 2) & 7) << 3)];
    }
#pragma unroll
    for (int og = 0; og < 4; ++og)
#pragma unroll
      for (int ng = 0; ng < 8; ++ng)
        acc[og][ng] = MFMAH(wf[og], xf[ng], acc[og][ng]);
  }

#pragma unroll
  for (int og = 0; og < 4; ++og) {
    float4 b4 = *(const float4*)&bias[wv * 64 + og * 16 + quad * 4];
#pragma unroll
    for (int ng = 0; ng < 8; ++ng) {
      const int n = n0 + ng * 16 + l16;
      if (p == 2) {
#pragma unroll
        for (int r = 0; r < 4; ++r) {
          int o = wv * 64 + og * 16 + quad * 4 + r;
          float y = acc[og][ng][r] + ((const float*)&b4)[r];
          Vh[((size_t)(b * CDIM + o)) * NDIM + n] = (_Float16)y;
        }
      } else {
        half4 h4;
#pragma unroll
        for (int r = 0; r < 4; ++r)
          h4[r] = (_Float16)(acc[og][ng][r] + ((const float*)&b4)[r]);
        size_t idx = ((size_t)(b * NDIM + n)) * CDIM + wv * 64 + og * 16 + quad * 4;
        if (p == 0) *(half4*)&Qh[idx] = h4;
        else        *(half4*)&Kh[idx] = h4;
      }
    }
  }
}

// ---------------------------------------------------------------------------
// Flash attention, kf-amortized: ONE block per CU, i-range 128 per block.
// Theory: the kernel is LDS-read-BW bound, dominated by every wave re-reading
// the full K tile. Here each wave's kf fragment feeds TWO i-groups
// (sA/sB share kf) -> per-CU kf traffic for 128 i halves (256->128 b128/jt).
// Per-SIMD MFMA and VALU cycles are unchanged vs the 2-block layout.
//  - grid 256 = 8b x 32 it; blk&7=b -> all blocks of batch b on one XCD
//    (round-robin dispatch), K/V L2-resident; 1 block per CU, no tail.
//  - launch_bounds(256,1): 1 wave/SIMD -> up to 512 VGPR, ~300 live, no spill
//    (WRITE_SIZE is the canary; r5 spilled at 116 VGPR budget, this avoids it).
//  - Ps/Al single-buffered (52 KB LDS): the 2 barriers already separate
//    PV(jt-1) reads [before B1] from softmax(jt) writes [after B1], and
//    kf reads(jt) [before B2] from DMA(jt+1) issue [after B2].
//  - K staging via global_load_lds DMA + source-content swizzle (round-6,
//    proven); exp2-domain softmax (proven, absmax unchanged).
// ---------------------------------------------------------------------------
__global__ __launch_bounds__(256, 1) void attn_kernel(
    const float* __restrict__ queries, const float* __restrict__ mask,
    const _Float16* __restrict__ Qh, const _Float16* __restrict__ Kh,
    const _Float16* __restrict__ Vh, float* __restrict__ out)
{
  const int blk = blockIdx.x, b = blk & 7, it = blk >> 3;  // 256 blocks
  const int i0 = it * 128;

  __shared__ __align__(16) _Float16 Ks[64 * 256];   // linear, swizzled content
  __shared__ __align__(16) _Float16 Ps[128][72];    // [i][j] 18432 B (single)
  __shared__ __align__(16) float Al[128];           // alpha per i-row
  __shared__ __align__(16) float Li[128];           // 1/l per i-row

  const int tid = threadIdx.x;
  const int wv = tid >> 6, lane = tid & 63, l16 = lane & 15, quad = lane >> 4;

  const float LOG2E = 1.44269504088896f;

  // Q fragments, two 16-row i-groups per wave: A = i0+wv*32+l16, B = A+16
  half8 qfA[8], qfB[8];
  {
    const size_t qrA = ((size_t)(b * NDIM + i0 + wv * 32 + l16)) * CDIM;
    const size_t qrB = qrA + (size_t)16 * CDIM;
#pragma unroll
    for (int kc = 0; kc < 8; ++kc) {
      qfA[kc] = *(const half8*)(Qh + qrA + kc * 32 + quad * 8);
      qfB[kc] = *(const half8*)(Qh + qrB + kc * 32 + quad * 8);
    }
  }
  const float mvalA = mask[(size_t)b * NDIM + i0 + wv * 32 + l16] * LOG2E;
  const float mvalB = mask[(size_t)b * NDIM + i0 + wv * 32 + 16 + l16] * LOG2E;
  float mA = -1e30f, lA = 0.f, mB = -1e30f, lB = 0.f;

  // O: all 128 i x c-slice [wv*64,+64). O[g][cg]: i = i0+g*16+quad*4+r,
  // c = wv*64+cg*16+l16. 128 VGPR.
  f32x4 O[8][4];
#pragma unroll
  for (int g = 0; g < 8; ++g)
#pragma unroll
    for (int cg = 0; cg < 4; ++cg) O[g][cg] = (f32x4){0.f, 0.f, 0.f, 0.f};

  const _Float16* __restrict__ Kb = Kh + (size_t)b * NDIM * CDIM;
  const _Float16* __restrict__ Vw = Vh + ((size_t)(b * CDIM + wv * 64)) * NDIM;

  // staging geometry (loop-invariant); source col pre-swizzled so linear LDS
  // + swizzled ds_read is conflict-spread (round-6 proven).
  const int jrow = tid >> 5;                                   // 0..7
  const int scol = ((tid & 31) * 8) ^ ((jrow & 7) << 3);       // halfs
  char* const ldst0 = (char*)Ks + (size_t)tid * 16;            // +st*4096
  const int kswz = (l16 & 7) << 3;                             // read-side XOR

  // prologue: issue DMA for K tile 0
#pragma unroll
  for (int st = 0; st < 8; ++st)
    GLOAD_LDS16(Kb + (size_t)(st * 8 + jrow) * CDIM + scol, ldst0 + st * 4096);

  for (int jt = 0; jt < 64; ++jt) {
    const int j0 = jt * 64;
    // V fragments for this tile direct from global (held across QK/softmax)
    half8 vf[2][4];
#pragma unroll
    for (int kk = 0; kk < 2; ++kk)
#pragma unroll
      for (int cg = 0; cg < 4; ++cg)
        vf[kk][cg] = *(const half8*)(Vw + (size_t)(cg * 16 + l16) * NDIM + j0 + kk * 32 + quad * 8);
    __syncthreads();  // B1: K DMA drained; Ps/Al free (PV(jt-1) done)

    // S^T = K Q^T for BOTH i-groups from one kf read (the kf-amortization)
    f32x4 sA[4], sB[4];
#pragma unroll
    for (int js = 0; js < 4; ++js) {
      sA[js] = (f32x4){0.f, 0.f, 0.f, 0.f};
      sB[js] = (f32x4){0.f, 0.f, 0.f, 0.f};
    }
#pragma unroll
    for (int kc = 0; kc < 8; ++kc) {
#pragma unroll
      for (int js = 0; js < 4; ++js) {
        half8 kf = *(const half8*)&Ks[(js * 16 + l16) * 256 + ((kc * 32 + quad * 8) ^ kswz)];
        sA[js] = MFMAH(kf, qfA[kc], sA[js]);
        sB[js] = MFMAH(kf, qfB[kc], sB[js]);
      }
    }

    // online softmax (exp2 domain), group A then group B
    {
      float a[16];
      float mx = -1e30f;
#pragma unroll
      for (int js = 0; js < 4; ++js)
#pragma unroll
        for (int r = 0; r < 4; ++r) {
          float v = sA[js][r] * mvalA;
          a[js * 4 + r] = v;
          mx = fmaxf(mx, v);
        }
      mx = fmaxf(mx, __shfl_xor(mx, 16));
      mx = fmaxf(mx, __shfl_xor(mx, 32));
      const float mnew = fmaxf(mA, mx);
      const float alpha = exp2f(mA - mnew);
      mA = mnew;
      float psum = 0.f;
#pragma unroll
      for (int js = 0; js < 4; ++js) {
        float p0 = exp2f(a[js * 4 + 0] - mnew);
        float p1 = exp2f(a[js * 4 + 1] - mnew);
        float p2 = exp2f(a[js * 4 + 2] - mnew);
        float p3 = exp2f(a[js * 4 + 3] - mnew);
        psum += (p0 + p1) + (p2 + p3);
        half4 hp = {(_Float16)p0, (_Float16)p1, (_Float16)p2, (_Float16)p3};
        *(half4*)&Ps[wv * 32 + l16][js * 16 + quad * 4] = hp;
      }
      psum += __shfl_xor(psum, 16);
      psum += __shfl_xor(psum, 32);
      lA = lA * alpha + psum;
      if (quad == 0) Al[wv * 32 + l16] = alpha;
    }
    {
      float a[16];
      float mx = -1e30f;
#pragma unroll
      for (int js = 0; js < 4; ++js)
#pragma unroll
        for (int r = 0; r < 4; ++r) {
          float v = sB[js][r] * mvalB;
          a[js * 4 + r] = v;
          mx = fmaxf(mx, v);
        }
      mx = fmaxf(mx, __shfl_xor(mx, 16));
      mx = fmaxf(mx, __shfl_xor(mx, 32));
      const float mnew = fmaxf(mB, mx);
      const float alpha = exp2f(mB - mnew);
      mB = mnew;
      float psum = 0.f;
#pragma unroll
      for (int js = 0; js < 4; ++js) {
        float p0 = exp2f(a[js * 4 + 0] - mnew);
        float p1 = exp2f(a[js * 4 + 1] - mnew);
        float p2 = exp2f(a[js * 4 + 2] - mnew);
        float p3 = exp2f(a[js * 4 + 3] - mnew);
        psum += (p0 + p1) + (p2 + p3);
        half4 hp = {(_Float16)p0, (_Float16)p1, (_Float16)p2, (_Float16)p3};
        *(half4*)&Ps[wv * 32 + 16 + l16][js * 16 + quad * 4] = hp;
      }
      psum += __shfl_xor(psum, 16);
      psum += __shfl_xor(psum, 32);
      lB = lB * alpha + psum;
      if (quad == 0) Al[wv * 32 + 16 + l16] = alpha;
    }
    __syncthreads();  // B2: Ps/Al visible; all kf reads of jt complete

    // issue NEXT K tile's DMA -> latency hidden under PV (round-6 proven)
    if (jt < 63) {
      const _Float16* srcn = Kb + (size_t)((jt + 1) * 64 + jrow) * CDIM + scol;
#pragma unroll
      for (int st = 0; st < 8; ++st)
        GLOAD_LDS16(srcn + (size_t)st * 8 * CDIM, ldst0 + st * 4096);
    }

    // O rescale (all 128 i) + O += P V
    f32x4 av[8];
#pragma unroll
    for (int g = 0; g < 8; ++g) av[g] = *(const f32x4*)&Al[g * 16 + quad * 4];
#pragma unroll
    for (int g = 0; g < 8; ++g)
#pragma unroll
      for (int cg = 0; cg < 4; ++cg)
#pragma unroll
        for (int r = 0; r < 4; ++r) O[g][cg][r] *= av[g][r];
#pragma unroll
    for (int kk = 0; kk < 2; ++kk) {
      half8 pa[8];
#pragma unroll
      for (int g = 0; g < 8; ++g)
        pa[g] = *(const half8*)&Ps[g * 16 + l16][kk * 32 + quad * 8];
#pragma unroll
      for (int g = 0; g < 8; ++g)
#pragma unroll
        for (int cg = 0; cg < 4; ++cg)
          O[g][cg] = MFMAH(pa[g], vf[kk][cg], O[g][cg]);
    }
  }

  // publish 1/l, then blended epilogue over all 128 i
  if (quad == 0) {
    Li[wv * 32 + l16] = 1.0f / lA;
    Li[wv * 32 + 16 + l16] = 1.0f / lB;
  }
  __syncthreads();
#pragma unroll
  for (int g = 0; g < 8; ++g) {
    f32x4 li4 = *(const f32x4*)&Li[g * 16 + quad * 4];
    const int i = i0 + g * 16 + quad * 4;
    float4 m4 = *(const float4*)&mask[(size_t)b * NDIM + i];
#pragma unroll
    for (int cg = 0; cg < 4; ++cg) {
      const int c = wv * 64 + cg * 16 + l16;
      const size_t base = ((size_t)(b * CDIM + c)) * NDIM + i;
      float4 q4 = *(const float4*)(queries + base);
      float4 o4;
      o4.x = q4.x * m4.x + (1.f - m4.x) * (O[g][cg][0] * li4[0]);
      o4.y = q4.y * m4.y + (1.f - m4.y) * (O[g][cg][1] * li4[1]);
      o4.z = q4.z * m4.z + (1.f - m4.z) * (O[g][cg][2] * li4[2]);
      o4.w = q4.w * m4.w + (1.f - m4.w) * (O[g][cg][3] * li4[3]);
      *(float4*)(out + base) = o4;
    }
  }
}

extern "C" void kernel_launch(void* const* d_in, const int* in_sizes, int n_in,
                              void* d_out, int out_size, void* d_ws, size_t ws_size,
                              hipStream_t stream) {
  const float* queries = (const float*)d_in[0];
  const float* keys    = (const float*)d_in[1];
  const float* mask    = (const float*)d_in[2];
  const float* Wq = (const float*)d_in[3];
  const float* bq = (const float*)d_in[4];
  const float* Wk = (const float*)d_in[5];
  const float* bk = (const float*)d_in[6];
  const float* Wv = (const float*)d_in[7];
  const float* bv = (const float*)d_in[8];
  float* out = (float*)d_out;

  const size_t elems = (size_t)8 * NDIM * CDIM;
  _Float16* Qh = (_Float16*)d_ws;
  _Float16* Kh = Qh + elems;
  _Float16* Vh = Kh + elems;
  _Float16* Wc = Vh + elems;   // 3*65536 fp16

  cast_w_kernel<<<dim3(192), 256, 0, stream>>>(Wq, Wk, Wv, Wc);
  proj_kernel<<<dim3(32, 1, 24), 256, 0, stream>>>(
      queries, keys, Wc, bq, bk, bv, Qh, Kh, Vh);
  attn_kernel<<<dim3(256), 256, 0, stream>>>(
      queries, mask, Qh, Kh, Vh, out);
}